// Round 1
// baseline (1283.801 us; speedup 1.0000x reference)
//
#include <hip/hip_runtime.h>
#include <hip/hip_bf16.h>
#include <stdint.h>

// Problem dims (fixed by reference): X[8,2048,4096] f32, W 4-bit packed [4096,4096],
// scales/zp [4096,32] (group=128), bias[4096]. out = X @ W^T + bias, f32.
#define M_DIM 16384
#define N_DIM 4096
#define K_DIM 4096
#define NG 32
#define GS 128

#define BM 128
#define BN 128
#define BK 64

typedef short bf16x8 __attribute__((ext_vector_type(8)));
typedef float f32x4 __attribute__((ext_vector_type(4)));

__device__ __forceinline__ uint32_t f32_to_bf16_rne(float f) {
    union { float f; uint32_t u; } v; v.f = f;
    uint32_t u = v.u;
    return (u + 0x7FFFu + ((u >> 16) & 1u)) >> 16;
}

__device__ __forceinline__ uint32_t pack2_bf16(float a, float b) {
    return f32_to_bf16_rne(a) | (f32_to_bf16_rne(b) << 16);
}

// ---------------- pass 1: X f32 -> bf16 (8 elems/thread) ----------------
__global__ __launch_bounds__(256) void convert_x_kernel(const float* __restrict__ x,
                                                        uint32_t* __restrict__ xb) {
    size_t t = (size_t)blockIdx.x * 256 + threadIdx.x;   // 0 .. M*K/8-1
    const float4* src = (const float4*)x + t * 2;
    float4 a = src[0];
    float4 b = src[1];
    uint4 o;
    o.x = pack2_bf16(a.x, a.y);
    o.y = pack2_bf16(a.z, a.w);
    o.z = pack2_bf16(b.x, b.y);
    o.w = pack2_bf16(b.z, b.w);
    ((uint4*)xb)[t] = o;
}

// ---------------- pass 2: W int4-packed -> bf16 (8 weights/thread) ----------------
// packed byte b (stored as int32): low nibble = even flat index, high = odd.
// w[o][i] = scale[o][i/128] * (q - zp[o][i/128])
__global__ __launch_bounds__(256) void dequant_w_kernel(const int* __restrict__ wq,
                                                        const float* __restrict__ sc,
                                                        const int* __restrict__ zp,
                                                        uint32_t* __restrict__ wb) {
    size_t t = (size_t)blockIdx.x * 256 + threadIdx.x;   // 0 .. O*I/8-1
    size_t f0 = t * 8;                                   // flat weight index
    int o = (int)(f0 >> 12);                             // / 4096
    int i0 = (int)(f0 & 4095);
    int g = i0 >> 7;                                     // 8 consecutive i stay in one group
    float s = sc[o * NG + g];
    float z = (float)zp[o * NG + g];
    int4 b = ((const int4*)wq)[t];
    int bb0 = b.x, bb1 = b.y, bb2 = b.z, bb3 = b.w;
    uint4 r;
    r.x = pack2_bf16(s * ((float)(bb0 & 15) - z), s * ((float)((bb0 >> 4) & 15) - z));
    r.y = pack2_bf16(s * ((float)(bb1 & 15) - z), s * ((float)((bb1 >> 4) & 15) - z));
    r.z = pack2_bf16(s * ((float)(bb2 & 15) - z), s * ((float)((bb2 >> 4) & 15) - z));
    r.w = pack2_bf16(s * ((float)(bb3 & 15) - z), s * ((float)((bb3 >> 4) & 15) - z));
    ((uint4*)wb)[t] = r;
}

// ---------------- pass 3: bf16 GEMM, C = A * B^T + bias ----------------
// A [M][K] row-major bf16, B [N][K] row-major bf16 (i.e. W), C [M][N] f32.
// m97 structure: 128x128 tile, BK=64, 4 waves (2x2 of 64x64), global_load_lds w=16,
// 16x16x32 bf16 MFMA, 4x4 frags/wave, 2 barriers per K-step.
__global__ __launch_bounds__(256) void gemm_kernel(const unsigned short* __restrict__ A,
                                                   const unsigned short* __restrict__ B,
                                                   const float* __restrict__ bias,
                                                   float* __restrict__ C) {
    __shared__ __align__(16) unsigned short Asm[BM * BK];   // 16 KB
    __shared__ __align__(16) unsigned short Bsm[BN * BK];   // 16 KB

    // XCD-aware bijective swizzle (nwg = 4096, divisible by 8), then
    // decompose so consecutive swz share the same A panel (iterate bn fastest).
    int bid = blockIdx.x;
    int cpx = gridDim.x >> 3;                 // 512
    int swz = (bid & 7) * cpx + (bid >> 3);
    int bm = swz / (N_DIM / BN);
    int bn = swz % (N_DIM / BN);
    int m0 = bm * BM, n0 = bn * BN;

    int tid = threadIdx.x;
    int wid = tid >> 6, lane = tid & 63;
    int wr = wid >> 1, wc = wid & 1;          // wave -> 64x64 quadrant
    int lr = lane & 15;                       // fragment row (A-row / B-row=C-col)
    int q  = lane >> 4;                       // k sub-chunk 0..3

    f32x4 acc[4][4];
#pragma unroll
    for (int m = 0; m < 4; ++m)
#pragma unroll
        for (int n = 0; n < 4; ++n)
            acc[m][n] = (f32x4){0.f, 0.f, 0.f, 0.f};

    const unsigned short* Ag = A + (size_t)m0 * K_DIM;
    const unsigned short* Bg = B + (size_t)n0 * K_DIM;

    for (int kt = 0; kt < K_DIM / BK; ++kt) {
        int k0 = kt * BK;
        // stage: 128x64 bf16 per operand = 16KB; 256 thr * 16B * 4 iters
#pragma unroll
        for (int it = 0; it < 4; ++it) {
            int c = it * 256 + tid;           // chunk id, 8 bf16 each
            int row = c >> 3;
            int col = (c & 7) << 3;
            __builtin_amdgcn_global_load_lds(
                (const __attribute__((address_space(1))) void*)(Ag + (size_t)row * K_DIM + k0 + col),
                (__attribute__((address_space(3))) void*)(Asm + c * 8), 16, 0, 0);
            __builtin_amdgcn_global_load_lds(
                (const __attribute__((address_space(1))) void*)(Bg + (size_t)row * K_DIM + k0 + col),
                (__attribute__((address_space(3))) void*)(Bsm + c * 8), 16, 0, 0);
        }
        __syncthreads();

#pragma unroll
        for (int kk = 0; kk < 2; ++kk) {
            bf16x8 af[4], bfr[4];
#pragma unroll
            for (int m = 0; m < 4; ++m)
                af[m] = *(const bf16x8*)(Asm + (wr * 64 + m * 16 + lr) * BK + kk * 32 + q * 8);
#pragma unroll
            for (int n = 0; n < 4; ++n)
                bfr[n] = *(const bf16x8*)(Bsm + (wc * 64 + n * 16 + lr) * BK + kk * 32 + q * 8);
#pragma unroll
            for (int m = 0; m < 4; ++m)
#pragma unroll
                for (int n = 0; n < 4; ++n)
                    acc[m][n] = __builtin_amdgcn_mfma_f32_16x16x32_bf16(af[m], bfr[n], acc[m][n], 0, 0, 0);
        }
        __syncthreads();
    }

    // epilogue: D col = lane&15, row = (lane>>4)*4 + reg
#pragma unroll
    for (int n = 0; n < 4; ++n) {
        int col = n0 + wc * 64 + n * 16 + lr;
        float bv = bias[col];
#pragma unroll
        for (int m = 0; m < 4; ++m) {
            int rowb = m0 + wr * 64 + m * 16 + q * 4;
#pragma unroll
            for (int r = 0; r < 4; ++r)
                C[(size_t)(rowb + r) * N_DIM + col] = acc[m][n][r] + bv;
        }
    }
}

// ---------------- fallback (ws too small): fused, slow but correct ----------------
__global__ __launch_bounds__(256) void fallback_kernel(const float* __restrict__ x,
                                                       const int* __restrict__ wq,
                                                       const float* __restrict__ sc,
                                                       const int* __restrict__ zp,
                                                       const float* __restrict__ bias,
                                                       float* __restrict__ out) {
    __shared__ float xs[K_DIM];
    int m = blockIdx.x >> 4;
    int n = ((blockIdx.x & 15) << 8) + threadIdx.x;
    for (int k = threadIdx.x; k < K_DIM; k += 256)
        xs[k] = x[(size_t)m * K_DIM + k];
    __syncthreads();
    float acc = 0.f;
    const int* wrow = wq + ((size_t)n * K_DIM >> 1);
    for (int g = 0; g < NG; ++g) {
        float s = sc[n * NG + g];
        float z = (float)zp[n * NG + g];
        float ga = 0.f;
        for (int kb = 0; kb < GS / 2; ++kb) {
            int byte_ = wrow[g * (GS / 2) + kb];
            int k = g * GS + kb * 2;
            ga += xs[k]     * ((float)(byte_ & 15) - z);
            ga += xs[k + 1] * ((float)((byte_ >> 4) & 15) - z);
        }
        acc += s * ga;
    }
    out[(size_t)m * N_DIM + n] = acc + bias[n];
}

extern "C" void kernel_launch(void* const* d_in, const int* in_sizes, int n_in,
                              void* d_out, int out_size, void* d_ws, size_t ws_size,
                              hipStream_t stream) {
    const float* x    = (const float*)d_in[0];
    const int*   wq   = (const int*)d_in[1];
    const float* sc   = (const float*)d_in[2];
    const int*   zp   = (const int*)d_in[3];
    const float* bias = (const float*)d_in[4];
    float* out = (float*)d_out;

    size_t xb_elems = (size_t)M_DIM * K_DIM;          // bf16
    size_t wb_elems = (size_t)N_DIM * K_DIM;          // bf16
    size_t need = (xb_elems + wb_elems) * sizeof(unsigned short);   // 160 MB

    if (ws_size >= need) {
        unsigned short* xb = (unsigned short*)d_ws;
        unsigned short* wb = xb + xb_elems;
        convert_x_kernel<<<(int)(xb_elems / 8 / 256), 256, 0, stream>>>(x, (uint32_t*)xb);
        dequant_w_kernel<<<(int)(wb_elems / 8 / 256), 256, 0, stream>>>(wq, sc, zp, (uint32_t*)wb);
        gemm_kernel<<<(M_DIM / BM) * (N_DIM / BN), 256, 0, stream>>>(xb, wb, bias, out);
    } else {
        fallback_kernel<<<M_DIM * 16, 256, 0, stream>>>(x, wq, sc, zp, bias, out);
    }
}

// Round 2
// 1189.473 us; speedup vs baseline: 1.0793x; 1.0793x over previous
//
#include <hip/hip_runtime.h>
#include <hip/hip_bf16.h>
#include <stdint.h>

// out[16384,4096] = X[16384,4096] @ W^T + bias ; W int4 block-dequant (group=128)
#define M_DIM 16384
#define N_DIM 4096
#define K_DIM 4096
#define NG 32
#define GS 128

#define BM 256
#define BN 256
#define BK 32
#define NT (K_DIM / BK)          // 128 K-tiles
#define GRID ((M_DIM / BM) * (N_DIM / BN))   // 64*16 = 1024

typedef short bf16x8 __attribute__((ext_vector_type(8)));
typedef float f32x4 __attribute__((ext_vector_type(4)));
typedef unsigned short ushort;

__device__ __forceinline__ uint32_t f32_to_bf16_rne(float f) {
    union { float f; uint32_t u; } v; v.f = f;
    uint32_t u = v.u;
    return (u + 0x7FFFu + ((u >> 16) & 1u)) >> 16;
}
__device__ __forceinline__ uint32_t pack2_bf16(float a, float b) {
    return f32_to_bf16_rne(a) | (f32_to_bf16_rne(b) << 16);
}

// ---------------- pass 1: X f32 -> bf16, fully coalesced, grid-stride ----------------
__global__ __launch_bounds__(256) void convert_x_kernel(const float4* __restrict__ x,
                                                        uint2* __restrict__ xb) {
    const size_t total = (size_t)M_DIM * K_DIM / 4;          // float4 chunks
    const size_t stride = (size_t)gridDim.x * 256;
    for (size_t i = (size_t)blockIdx.x * 256 + threadIdx.x; i < total; i += stride) {
        float4 a = x[i];
        uint2 o;
        o.x = pack2_bf16(a.x, a.y);
        o.y = pack2_bf16(a.z, a.w);
        xb[i] = o;
    }
}

// ---------------- pass 2: W int4 -> bf16 dequant, grid-stride ----------------
// packed byte (one per int32): low nibble = even flat idx, high = odd.
__global__ __launch_bounds__(256) void dequant_w_kernel(const int4* __restrict__ wq4,
                                                        const float* __restrict__ sc,
                                                        const int* __restrict__ zp,
                                                        uint4* __restrict__ wb) {
    const size_t total = (size_t)N_DIM * K_DIM / 8;          // 8 weights per thread-iter
    const size_t stride = (size_t)gridDim.x * 256;
    for (size_t t = (size_t)blockIdx.x * 256 + threadIdx.x; t < total; t += stride) {
        size_t f0 = t * 8;
        int o = (int)(f0 >> 12);
        int g = (int)((f0 & 4095) >> 7);
        float s = sc[o * NG + g];
        float z = (float)zp[o * NG + g];
        int4 b = wq4[t];
        uint4 r;
        r.x = pack2_bf16(s * ((float)(b.x & 15) - z), s * ((float)((b.x >> 4) & 15) - z));
        r.y = pack2_bf16(s * ((float)(b.y & 15) - z), s * ((float)((b.y >> 4) & 15) - z));
        r.z = pack2_bf16(s * ((float)(b.z & 15) - z), s * ((float)((b.z >> 4) & 15) - z));
        r.w = pack2_bf16(s * ((float)(b.w & 15) - z), s * ((float)((b.w >> 4) & 15) - z));
        wb[t] = r;
    }
}

// ---------------- pass 3: bf16 GEMM  C = A * B^T + bias ----------------
// 256x256 tile, BK=32, 8 waves (2Mx4N), per-wave 128x64 C.
// Triple-buffered LDS (96KB), depth-2 prefetch, counted vmcnt (never 0 in
// steady state), raw s_barrier, setprio around MFMA cluster, XCD swizzle.
// BK=32 => 64B LDS row stride => ds_read_b128 frag reads hit bank-group
// (row&1)*4+q : uniform 8 lanes per 16B slot group = conflict-free, linear LDS.

__device__ __forceinline__ void stage_tile(const ushort* __restrict__ Ag,
                                           const ushort* __restrict__ Bg,
                                           int k0, ushort* As, ushort* Bs, int tid) {
#pragma unroll
    for (int i = 0; i < 2; ++i) {
        int c = i * 512 + tid;          // 16B chunk id, 1024 per operand tile
        int row = c >> 2;               // 4 chunks per 32-col row
        int cc = (c & 3) << 3;          // bf16 col
        __builtin_amdgcn_global_load_lds(
            (const __attribute__((address_space(1))) void*)(Ag + (size_t)row * K_DIM + k0 + cc),
            (__attribute__((address_space(3))) void*)(As + c * 8), 16, 0, 0);
        __builtin_amdgcn_global_load_lds(
            (const __attribute__((address_space(1))) void*)(Bg + (size_t)row * K_DIM + k0 + cc),
            (__attribute__((address_space(3))) void*)(Bs + c * 8), 16, 0, 0);
    }
}

__device__ __forceinline__ void compute_tile(const ushort* __restrict__ As,
                                             const ushort* __restrict__ Bs,
                                             int wr, int wc, int lr, int q,
                                             f32x4 acc[8][4]) {
    bf16x8 bf[4], af[8];
#pragma unroll
    for (int n = 0; n < 4; ++n)
        bf[n] = *(const bf16x8*)(Bs + (wc * 64 + n * 16 + lr) * BK + q * 8);
#pragma unroll
    for (int m = 0; m < 8; ++m)
        af[m] = *(const bf16x8*)(As + (wr * 128 + m * 16 + lr) * BK + q * 8);
    __builtin_amdgcn_s_setprio(1);
#pragma unroll
    for (int m = 0; m < 8; ++m)
#pragma unroll
        for (int n = 0; n < 4; ++n)
            acc[m][n] = __builtin_amdgcn_mfma_f32_16x16x32_bf16(af[m], bf[n], acc[m][n], 0, 0, 0);
    __builtin_amdgcn_s_setprio(0);
}

__global__ __launch_bounds__(512, 2) void gemm_kernel(const ushort* __restrict__ A,
                                                      const ushort* __restrict__ B,
                                                      const float* __restrict__ bias,
                                                      float* __restrict__ C) {
    __shared__ __align__(16) ushort As[3][BM * BK];   // 3 x 16KB
    __shared__ __align__(16) ushort Bs[3][BN * BK];   // 3 x 16KB

    // XCD-aware bijective swizzle (1024 % 8 == 0); bm fastest so each XCD's
    // contiguous chunk shares 2 W-panels (4MB, L2-resident) across all bm.
    int bid = blockIdx.x;
    int swz = (bid & 7) * (GRID / 8) + (bid >> 3);
    int bm = swz & 63;                // M/BM = 64
    int bn = swz >> 6;                // N/BN = 16
    int m0 = bm * BM, n0 = bn * BN;

    int tid = threadIdx.x;
    int wid = tid >> 6, lane = tid & 63;
    int wr = wid >> 2, wc = wid & 3;  // 2x4 wave grid, wave owns 128x64
    int lr = lane & 15;
    int q = lane >> 4;

    f32x4 acc[8][4];
#pragma unroll
    for (int m = 0; m < 8; ++m)
#pragma unroll
        for (int n = 0; n < 4; ++n)
            acc[m][n] = (f32x4){0.f, 0.f, 0.f, 0.f};

    const ushort* Ag = A + (size_t)m0 * K_DIM;
    const ushort* Bg = B + (size_t)n0 * K_DIM;

    // prologue: stage tiles 0,1
    stage_tile(Ag, Bg, 0, As[0], Bs[0], tid);
    stage_tile(Ag, Bg, BK, As[1], Bs[1], tid);

    for (int t = 0; t < NT; ++t) {
        int s = t % 3;
        if (t + 2 < NT) {
            int s2 = (t + 2) % 3;
            stage_tile(Ag, Bg, (t + 2) * BK, As[s2], Bs[s2], tid);
            // outstanding: tile t+1 (4) + tile t+2 (4); wait tile t done
            asm volatile("s_waitcnt vmcnt(8)" ::: "memory");
        } else if (t + 1 < NT) {
            asm volatile("s_waitcnt vmcnt(4)" ::: "memory");
        } else {
            asm volatile("s_waitcnt vmcnt(0)" ::: "memory");
        }
        __builtin_amdgcn_s_barrier();           // tile t visible to all waves
        compute_tile(As[s], Bs[s], wr, wc, lr, q, acc);
        __builtin_amdgcn_s_barrier();           // all reads of slot s done
    }

    // epilogue: C row = (lane>>4)*4 + reg, col = lane&15 within each 16x16 frag
#pragma unroll
    for (int n = 0; n < 4; ++n) {
        int col = n0 + wc * 64 + n * 16 + lr;
        float bv = bias[col];
#pragma unroll
        for (int m = 0; m < 8; ++m) {
            int rowb = m0 + wr * 128 + m * 16 + q * 4;
#pragma unroll
            for (int r = 0; r < 4; ++r)
                C[(size_t)(rowb + r) * N_DIM + col] = acc[m][n][r] + bv;
        }
    }
}

// ---------------- fallback (ws too small): fused, slow but correct ----------------
__global__ __launch_bounds__(256) void fallback_kernel(const float* __restrict__ x,
                                                       const int* __restrict__ wq,
                                                       const float* __restrict__ sc,
                                                       const int* __restrict__ zp,
                                                       const float* __restrict__ bias,
                                                       float* __restrict__ out) {
    __shared__ float xs[K_DIM];
    int m = blockIdx.x >> 4;
    int n = ((blockIdx.x & 15) << 8) + threadIdx.x;
    for (int k = threadIdx.x; k < K_DIM; k += 256)
        xs[k] = x[(size_t)m * K_DIM + k];
    __syncthreads();
    float acc = 0.f;
    const int* wrow = wq + ((size_t)n * K_DIM >> 1);
    for (int g = 0; g < NG; ++g) {
        float s = sc[n * NG + g];
        float z = (float)zp[n * NG + g];
        float ga = 0.f;
        for (int kb = 0; kb < GS / 2; ++kb) {
            int byte_ = wrow[g * (GS / 2) + kb];
            int k = g * GS + kb * 2;
            ga += xs[k]     * ((float)(byte_ & 15) - z);
            ga += xs[k + 1] * ((float)((byte_ >> 4) & 15) - z);
        }
        acc += s * ga;
    }
    out[(size_t)m * N_DIM + n] = acc + bias[n];
}

extern "C" void kernel_launch(void* const* d_in, const int* in_sizes, int n_in,
                              void* d_out, int out_size, void* d_ws, size_t ws_size,
                              hipStream_t stream) {
    const float* x    = (const float*)d_in[0];
    const int*   wq   = (const int*)d_in[1];
    const float* sc   = (const float*)d_in[2];
    const int*   zp   = (const int*)d_in[3];
    const float* bias = (const float*)d_in[4];
    float* out = (float*)d_out;

    size_t xb_elems = (size_t)M_DIM * K_DIM;
    size_t wb_elems = (size_t)N_DIM * K_DIM;
    size_t need = (xb_elems + wb_elems) * sizeof(ushort);   // 160 MB

    if (ws_size >= need) {
        ushort* xb = (ushort*)d_ws;
        ushort* wb = xb + xb_elems;
        convert_x_kernel<<<2048, 256, 0, stream>>>((const float4*)x, (uint2*)xb);
        dequant_w_kernel<<<2048, 256, 0, stream>>>((const int4*)wq, sc, zp, (uint4*)wb);
        gemm_kernel<<<GRID, 512, 0, stream>>>(xb, wb, bias, out);
    } else {
        fallback_kernel<<<M_DIM * 16, 256, 0, stream>>>(x, wq, sc, zp, bias, out);
    }
}